// Round 9
// baseline (741.975 us; speedup 1.0000x reference)
//
#include <hip/hip_runtime.h>
#include <stdint.h>

#define B    512
#define N    50257
#define BLK  512
#define NWAVE 8
#define TILE 4096            // stage 32 KB; total LDS ~39 KB -> 4 blocks/CU
#define CHUNK 512            // per-wave contiguous chunk = TILE/NWAVE
#define NGRP 8               // 64-elem groups per chunk
#define NT_TOTAL 13          // ceil(N/TILE): 12 full + 1105 tail
#define SEG0_T 7             // seg0 = tiles 0..6, seg1 = tiles 7..12
#define SEGBOUND (SEG0_T * TILE)   // 28672
#define THRESH 0.4f

// Softmax weights are strictly positive floats: raw bit pattern is monotone
// in value. Complement -> ascending stable order == descending weight order,
// ties broken by ascending original index (stable LSD radix), matching
// jnp.argsort(-weights).
__device__ __forceinline__ uint32_t sort_key(float w) { return ~__float_as_uint(w); }

// ---------------------------------------------------------------------------
// Histogram kernel: all-4-pass digit histograms + pass-1 seg0 digit counts.
// ---------------------------------------------------------------------------
__device__ __forceinline__ void hist_elem2(uint32_t* hw0, uint32_t* hs,
                                           const float w, const bool inSeg0) {
    const uint32_t key = sort_key(w);
    atomicAdd(hw0 + (key & 255u), 1u);
    atomicAdd(hw0 + 256 + ((key >> 8) & 255u), 1u);
    atomicAdd(hw0 + 512 + ((key >> 16) & 255u), 1u);
    atomicAdd(hw0 + 768 + ((key >> 24) & 255u), 1u);
    if (inSeg0) atomicAdd(hs + (key & 255u), 1u);
}

__global__ __launch_bounds__(BLK) void hist4_fast(const float* __restrict__ wts,
                                                  uint32_t* __restrict__ histWS,
                                                  uint32_t* __restrict__ segCnt0) {
    __shared__ uint32_t hw[NWAVE][4][256];   // 32 KB
    __shared__ uint32_t hseg[NWAVE][256];    //  8 KB
    __shared__ uint32_t wtot[4];
    const int row = blockIdx.x;
    const size_t base = (size_t)row * N;
    const int tid = threadIdx.x;
    const int lane = tid & 63;
    const int wv = tid >> 6;

    {   // zero own wave's slices (no cross-wave access -> no barrier needed)
        uint32_t* p = &hw[wv][0][0];
        for (int j = lane; j < 4 * 256; j += 64) p[j] = 0;
        uint32_t* q = &hseg[wv][0];
        for (int j = lane; j < 256; j += 64) q[j] = 0;
    }
    uint32_t* hw0 = &hw[wv][0][0];
    uint32_t* hs  = &hseg[wv][0];

    // vectorized sweep: head to 16B alignment, f4 body, tail
    const int head = (int)((4 - (base & 3)) & 3);
    for (int i = tid; i < head; i += BLK) hist_elem2(hw0, hs, wts[base + i], i < SEGBOUND);
    const int nvec = (N - head) >> 2;
    const float4* v4 = (const float4*)(wts + base + head);
    for (int iv = tid; iv < nvec; iv += BLK) {
        const float4 f = v4[iv];
        const int p0 = head + 4 * iv;
        hist_elem2(hw0, hs, f.x, p0 + 0 < SEGBOUND);
        hist_elem2(hw0, hs, f.y, p0 + 1 < SEGBOUND);
        hist_elem2(hw0, hs, f.z, p0 + 2 < SEGBOUND);
        hist_elem2(hw0, hs, f.w, p0 + 3 < SEGBOUND);
    }
    for (int i = head + 4 * nvec + tid; i < N; i += BLK)
        hist_elem2(hw0, hs, wts[base + i], i < SEGBOUND);
    __syncthreads();

    // pass-1 seg0 counts (overwrite, single block per row)
    if (tid < 256) {
        uint32_t c = 0;
        #pragma unroll
        for (int w = 0; w < NWAVE; ++w) c += hseg[w][tid];
        segCnt0[(size_t)row * 256 + tid] = c;   // pass-0 slot
    }

    for (int p = 0; p < 4; ++p) {
        uint32_t cnt = 0;
        if (tid < 256) {
            #pragma unroll
            for (int w = 0; w < NWAVE; ++w) cnt += hw[w][p][tid];
        }
        // exclusive scan over 256 bins: intra-wave shfl + cross-wave via wtot
        uint32_t incl = cnt;
        #pragma unroll
        for (int o = 1; o < 64; o <<= 1) {
            const uint32_t u = __shfl_up(incl, o);
            if (lane >= o) incl += u;
        }
        if (tid < 256 && lane == 63) wtot[tid >> 6] = incl;
        __syncthreads();
        if (tid < 256) {
            uint32_t prefix = 0;
            const int w4 = tid >> 6;
            #pragma unroll
            for (int w2 = 0; w2 < 4; ++w2) if (w2 < w4) prefix += wtot[w2];
            histWS[((size_t)row * 4 + p) * 256 + tid] = prefix + incl - cnt;
        }
        __syncthreads();   // protect wtot reuse
    }
}

// ---------------------------------------------------------------------------
// TIER A: segmented (2 blocks/row) pipelined wave-private scatter on packed
// u64 (key<<16|idx). Block (row,seg) owns tiles [t0,t1); cursor start =
// histWS + (seg ? segCur[row][d] : 0). Non-LAST passes count next-pass digits
// of outputs landing in seg0 (cnt0 LDS, one global atomicAdd/digit at end).
// Stability: blocks write disjoint, order-correct position ranges.
// ---------------------------------------------------------------------------
template <int SHIFT, bool FIRST, bool LAST>
__global__ __launch_bounds__(BLK, 8) void scatter_seg(const float* __restrict__ wts,
                                                      const unsigned long long* __restrict__ src,
                                                      unsigned long long* __restrict__ dst,
                                                      uint32_t* __restrict__ outIdx,
                                                      float* __restrict__ outW,
                                                      const uint32_t* __restrict__ histWS,
                                                      const uint32_t* __restrict__ segCur,
                                                      uint32_t* __restrict__ segNext) {
    __shared__ __align__(16) unsigned long long stage[TILE];  // 32 KB
    __shared__ uint16_t waveCnt[NWAVE][256];                  //  4 KB
    __shared__ uint32_t delta[256];                           //  1 KB
    __shared__ uint32_t cnt0[256];                            //  1 KB
    __shared__ uint32_t wtot[4];

    const int row = blockIdx.x;
    const int seg = blockIdx.y;
    const size_t base = (size_t)row * N;
    const int tid  = threadIdx.x;
    const int lane = tid & 63;
    const int wv   = tid >> 6;
    constexpr int PASS = SHIFT / 8;
    constexpr int KS = SHIFT + 16;   // digit position within packed pair

    const int t0 = seg ? SEG0_T : 0;
    const int t1 = seg ? NT_TOTAL : SEG0_T;

    uint32_t curReg = 0;             // this thread's bucket cursor (tid<256)
    if (tid < 256) {
        curReg = histWS[((size_t)row * 4 + PASS) * 256 + tid];
        if (seg) curReg += segCur[(size_t)row * 256 + tid];
        cnt0[tid] = 0;
    }

    unsigned long long pairN[NGRP];
    {   // prefetch first tile of this segment (t0 <= 7 -> always full)
        const int cb = t0 * TILE + wv * CHUNK;
        #pragma unroll
        for (int g = 0; g < NGRP; ++g) {
            const int i = cb + g * 64 + lane;
            pairN[g] = FIRST ? (((unsigned long long)sort_key(wts[base + i]) << 16) | (uint32_t)i)
                             : src[base + i];
        }
    }

    for (int t = t0; t < t1; ++t) {
        const int tbase = t * TILE;
        const int tileLen = (N - tbase < TILE) ? (N - tbase) : TILE;
        const int cbase = tbase + wv * CHUNK;
        const bool full = (tbase + TILE <= N);

        // ---- Phase 1: rank own chunk from registers (NO barriers) ----
        {   // zero own wave's 256 u16 counters: 512 B = 64 lanes x 8 B
            uint2* z = (uint2*)&waveCnt[wv][0];
            z[lane] = make_uint2(0u, 0u);
        }
        unsigned long long pairR[NGRP];
        uint32_t posR[NGRP];
        #pragma unroll
        for (int g = 0; g < NGRP; ++g) pairR[g] = pairN[g];

        if (full) {
            #pragma unroll
            for (int g = 0; g < NGRP; ++g) {
                const uint32_t d = (uint32_t)(pairR[g] >> KS) & 255u;
                unsigned long long peers = ~0ull;
                #pragma unroll
                for (int bb = 0; bb < 8; ++bb) {
                    const unsigned long long bit = __ballot((d >> bb) & 1u);
                    peers &= ((d >> bb) & 1u) ? bit : ~bit;
                }
                const unsigned long long lower = peers & ((1ull << lane) - 1ull);
                const uint32_t cnt = (uint32_t)waveCnt[wv][d];
                posR[g] = cnt + (uint32_t)__popcll(lower);
                if (lower == 0ull) waveCnt[wv][d] = (uint16_t)(cnt + (uint32_t)__popcll(peers));
            }
        } else {
            #pragma unroll
            for (int g = 0; g < NGRP; ++g) {
                const int i = cbase + g * 64 + lane;
                const bool valid = (i < N);
                const uint32_t d = (uint32_t)(pairR[g] >> KS) & 255u;
                unsigned long long peers = __ballot(valid);
                #pragma unroll
                for (int bb = 0; bb < 8; ++bb) {
                    const unsigned long long bit = __ballot((d >> bb) & 1u);
                    peers &= ((d >> bb) & 1u) ? bit : ~bit;
                }
                const unsigned long long lower = peers & ((1ull << lane) - 1ull);
                uint32_t cnt = 0;
                if (valid) cnt = (uint32_t)waveCnt[wv][d];
                posR[g] = cnt + (uint32_t)__popcll(lower);
                if (valid && lower == 0ull) waveCnt[wv][d] = (uint16_t)(cnt + (uint32_t)__popcll(peers));
            }
        }
        __syncthreads();                               // (A) ranks done; stage(t-1) drained

        // ---- Phase 2: tile layout (shfl scan, 2 barriers) ----
        uint32_t run = 0;
        if (tid < 256) {
            #pragma unroll
            for (int w = 0; w < NWAVE; ++w) {
                const uint32_t c = (uint32_t)waveCnt[w][tid];
                waveCnt[w][tid] = (uint16_t)run;       // excl offset across waves
                run += c;
            }
        }
        uint32_t incl = run;
        #pragma unroll
        for (int o = 1; o < 64; o <<= 1) {
            const uint32_t u = __shfl_up(incl, o);
            if (lane >= o) incl += u;
        }
        if (tid < 256 && lane == 63) wtot[tid >> 6] = incl;
        __syncthreads();                               // (B)
        if (tid < 256) {
            uint32_t prefix = 0;
            const int w4 = tid >> 6;
            #pragma unroll
            for (int w2 = 0; w2 < 4; ++w2) if (w2 < w4) prefix += wtot[w2];
            const uint32_t ts = prefix + incl - run;   // tileStart[tid]
            delta[tid] = curReg - ts;                  // global = delta[d] + p
            curReg += run;
            #pragma unroll
            for (int w = 0; w < NWAVE; ++w)
                waveCnt[w][tid] = (uint16_t)((uint32_t)waveCnt[w][tid] + ts);
        }
        __syncthreads();                               // (C) layout ready

        // ---- Prefetch next tile (latency hides under phases 3-4; r5 spot) ----
        if (t + 1 < t1) {
            const int ncb = (t + 1) * TILE + wv * CHUNK;
            if (ncb + CHUNK <= N) {                    // wave-uniform branch
                #pragma unroll
                for (int g = 0; g < NGRP; ++g) {
                    const int i = ncb + g * 64 + lane;
                    pairN[g] = FIRST ? (((unsigned long long)sort_key(wts[base + i]) << 16) | (uint32_t)i)
                                     : src[base + i];
                }
            } else {
                #pragma unroll
                for (int g = 0; g < NGRP; ++g) {
                    const int i = ncb + g * 64 + lane;
                    unsigned long long pair = 0;
                    if (i < N)
                        pair = FIRST ? (((unsigned long long)sort_key(wts[base + i]) << 16) | (uint32_t)i)
                                     : src[base + i];
                    pairN[g] = pair;
                }
            }
        }

        // ---- Phase 3: stage bucket-contiguous in LDS ----
        if (full) {
            #pragma unroll
            for (int g = 0; g < NGRP; ++g) {
                const uint32_t d = (uint32_t)(pairR[g] >> KS) & 255u;
                stage[(uint32_t)waveCnt[wv][d] + posR[g]] = pairR[g];
            }
        } else {
            #pragma unroll
            for (int g = 0; g < NGRP; ++g) {
                const int i = cbase + g * 64 + lane;
                if (i < N) {
                    const uint32_t d = (uint32_t)(pairR[g] >> KS) & 255u;
                    stage[(uint32_t)waveCnt[wv][d] + posR[g]] = pairR[g];
                }
            }
        }
        __syncthreads();                               // (D) stage complete

        // ---- Phase 4: 2-wide flush + next-pass seg0 digit instrumentation ----
        const int tileLenEven = tileLen & ~1;
        for (int p0 = 2 * tid; p0 < tileLenEven; p0 += 2 * BLK) {
            const ulonglong2 two = *(const ulonglong2*)&stage[p0];   // 16B aligned
            const uint32_t d0 = (uint32_t)(two.x >> KS) & 255u;
            const uint32_t d1 = (uint32_t)(two.y >> KS) & 255u;
            const uint32_t g0 = delta[d0] + (uint32_t)p0;
            const uint32_t g1 = delta[d1] + (uint32_t)p0 + 1u;
            if (LAST) {
                outIdx[base + g0] = (uint32_t)(two.x & 0xFFFFull);
                outW[base + g0]   = __uint_as_float(~(uint32_t)(two.x >> 16));
                outIdx[base + g1] = (uint32_t)(two.y & 0xFFFFull);
                outW[base + g1]   = __uint_as_float(~(uint32_t)(two.y >> 16));
            } else {
                dst[base + g0] = two.x;
                dst[base + g1] = two.y;
                if (g0 < SEGBOUND) atomicAdd(&cnt0[(uint32_t)(two.x >> (KS + 8)) & 255u], 1u);
                if (g1 < SEGBOUND) atomicAdd(&cnt0[(uint32_t)(two.y >> (KS + 8)) & 255u], 1u);
            }
        }
        for (int p = tileLenEven + tid; p < tileLen; p += BLK) {     // odd tail
            const unsigned long long pair = stage[p];
            const uint32_t d = (uint32_t)(pair >> KS) & 255u;
            const uint32_t g = delta[d] + (uint32_t)p;
            if (LAST) {
                outIdx[base + g] = (uint32_t)(pair & 0xFFFFull);
                outW[base + g]   = __uint_as_float(~(uint32_t)(pair >> 16));
            } else {
                dst[base + g] = pair;
                if (g < SEGBOUND) atomicAdd(&cnt0[(uint32_t)(pair >> (KS + 8)) & 255u], 1u);
            }
        }
        // no trailing barrier: (A) of the next tile separates flush(t) reads
        // from stage(t+1) writes and delta(t+1) updates.
    }

    if (!LAST) {   // publish this block's seg0 digit counts for the next pass
        __syncthreads();
        if (tid < 256) {
            const uint32_t c = cnt0[tid];
            if (c) atomicAdd(&segNext[(size_t)row * 256 + tid], c);
        }
    }
}

// ---------------------------------------------------------------------------
// Merged scan + normalize + idx->float (in place), block per row.
// out0 holds u32 idx, out1 holds sorted w on entry.
// ---------------------------------------------------------------------------
__global__ __launch_bounds__(BLK) void finalize_row(float* __restrict__ out0,
                                                    float* __restrict__ out1,
                                                    float* __restrict__ out2) {
    __shared__ float waveSum[NWAVE];
    __shared__ int   waveFirst[NWAVE];
    __shared__ float waveCum[NWAVE];
    __shared__ int   s_k;
    __shared__ float s_total;

    const int row = blockIdx.x;
    const size_t base = (size_t)row * N;
    const int tid  = threadIdx.x;
    const int lane = tid & 63;
    const int wv   = tid >> 6;

    if (tid == 0) { s_k = -1; s_total = 0.f; }
    __syncthreads();

    // Phase A: block-wide running cumsum with early exit
    float carry = 0.f;
    const int numTiles = (N + BLK - 1) / BLK;
    for (int t = 0; t < numTiles; ++t) {
        const int i = t * BLK + tid;
        const bool valid = (i < N);
        float w = valid ? out1[base + i] : 0.f;

        float s = w;
        #pragma unroll
        for (int o = 1; o < 64; o <<= 1) {
            float u = __shfl_up(s, o);
            if (lane >= o) s += u;
        }
        if (lane == 63) waveSum[wv] = s;
        __syncthreads();

        float prefix = 0.f, blockTot = 0.f;
        #pragma unroll
        for (int w2 = 0; w2 < NWAVE; ++w2) {
            float t2 = waveSum[w2];
            if (w2 < wv) prefix += t2;
            blockTot += t2;
        }
        const float cum = carry + prefix + s;

        const bool exceed = valid && (cum > THRESH);
        const unsigned long long bal = __ballot(exceed);
        const int fl = (bal == 0ull) ? 64 : (__ffsll(bal) - 1);
        if (lane == 0) waveFirst[wv] = fl;
        if (fl < 64 && lane == fl) waveCum[wv] = cum;
        __syncthreads();
        if (tid == 0) {
            for (int w2 = 0; w2 < NWAVE; ++w2) {
                if (waveFirst[w2] < 64) {
                    s_k = t * BLK + w2 * 64 + waveFirst[w2] + 1;
                    s_total = waveCum[w2];
                    break;
                }
            }
        }
        __syncthreads();
        if (s_k >= 0) break;
        carry += blockTot;
        __syncthreads();
    }

    int k = s_k;
    float total = s_total;
    if (k < 0) { k = N; total = carry; }
    const float inv = 1.0f / total;

    // Phase B: in-place convert + normalize, vectorized 16B (per-thread
    // read-before-write on identical addresses -> safe).
    const uint32_t* idxU = (const uint32_t*)out0;
    const int head = (int)((4 - (base & 3)) & 3);     // to 16B alignment
    const int nvec = (N - head) >> 2;
    const int vend = head + 4 * nvec;

    for (int i = tid; i < head; i += BLK) {           // head (<4 elems)
        const uint32_t idx = idxU[base + i];
        const float w = out1[base + i];
        out0[base + i] = (float)idx;
        out1[base + i] = (i < k) ? (w * inv) : 0.f;
    }
    const uint4*  ivp = (const uint4*)(idxU + base + head);
    float4*       o0v = (float4*)(out0 + base + head);
    float4*       o1v = (float4*)(out1 + base + head);
    for (int v = tid; v < nvec; v += BLK) {
        const uint4  iv = ivp[v];
        const float4 wv4 = o1v[v];
        const int i = head + 4 * v;
        float4 o0, o1;
        o0.x = (float)iv.x; o0.y = (float)iv.y; o0.z = (float)iv.z; o0.w = (float)iv.w;
        o1.x = (i + 0 < k) ? wv4.x * inv : 0.f;
        o1.y = (i + 1 < k) ? wv4.y * inv : 0.f;
        o1.z = (i + 2 < k) ? wv4.z * inv : 0.f;
        o1.w = (i + 3 < k) ? wv4.w * inv : 0.f;
        o0v[v] = o0;
        o1v[v] = o1;
    }
    for (int i = vend + tid; i < N; i += BLK) {       // tail (<4 elems)
        const uint32_t idx = idxU[base + i];
        const float w = out1[base + i];
        out0[base + i] = (float)idx;
        out1[base + i] = (i < k) ? (w * inv) : 0.f;
    }
    if (tid == 0) out2[row] = (float)k;
}

// ---------------------------------------------------------------------------
// TIER B (round-3 proven): subtile-ballot scatter on separate key/idx arrays.
// ---------------------------------------------------------------------------
#define NSUB (TILE / BLK)   // 8

template <int SHIFT, bool FIRST, bool LAST>
__global__ __launch_bounds__(BLK, 4) void scatter_tile(const float* __restrict__ wts,
                                                       const uint32_t* __restrict__ keySrc,
                                                       const uint16_t* __restrict__ idxSrc,
                                                       uint32_t* __restrict__ keyDst,
                                                       uint16_t* __restrict__ idxDst,
                                                       uint32_t* __restrict__ outIdx,
                                                       float* __restrict__ outW,
                                                       const uint32_t* __restrict__ histWS) {
    __shared__ uint32_t stageKey[TILE];
    __shared__ uint16_t stageIdx[TILE];
    __shared__ uint32_t waveCnt32[NWAVE][256];
    __shared__ uint16_t subOff[NSUB][256];
    __shared__ uint32_t cursor[256];
    __shared__ uint32_t tileCnt[256];
    __shared__ uint32_t tileStart[256];
    __shared__ uint32_t scanb[256];

    const int row = blockIdx.x;
    const size_t base = (size_t)row * N;
    const int tid  = threadIdx.x;
    const int lane = tid & 63;
    const int wv   = tid >> 6;
    constexpr int PASS = SHIFT / 8;

    if (tid < 256) cursor[tid] = histWS[((size_t)row * 4 + PASS) * 256 + tid];

    const int numTiles = (N + TILE - 1) / TILE;
    for (int t = 0; t < numTiles; ++t) {
        const int tbase = t * TILE;
        const int tileLen = (N - tbase < TILE) ? (N - tbase) : TILE;

        uint32_t keyR[NSUB];
        uint32_t idxR[NSUB];
        uint32_t posR[NSUB];

        #pragma unroll
        for (int s = 0; s < NSUB; ++s) {
            for (int j = tid; j < NWAVE * 256; j += BLK) ((uint32_t*)waveCnt32)[j] = 0;
            __syncthreads();

            const int i = tbase + s * BLK + tid;
            const bool valid = (i < N);
            uint32_t key = 0, idx = 0, d = 0;
            if (valid) {
                if (FIRST) { key = sort_key(wts[base + i]); idx = (uint32_t)i; }
                else       { key = keySrc[base + i]; idx = (uint32_t)idxSrc[base + i]; }
                d = (key >> SHIFT) & 255u;
            }
            keyR[s] = key;
            if (!FIRST) idxR[s] = idx;

            unsigned long long peers = __ballot(valid);
            #pragma unroll
            for (int b = 0; b < 8; ++b) {
                unsigned long long bit = __ballot(valid && ((d >> b) & 1u));
                peers &= ((d >> b) & 1u) ? bit : ~bit;
            }
            const unsigned long long lower = peers & ((1ull << lane) - 1ull);
            const uint32_t rank = (uint32_t)__popcll(lower);
            if (valid && lower == 0ull) waveCnt32[wv][d] = (uint32_t)__popcll(peers);
            __syncthreads();

            if (tid < 256) {
                uint32_t x = 0;
                #pragma unroll
                for (int w = 0; w < NWAVE; ++w) {
                    uint32_t c = waveCnt32[w][tid];
                    waveCnt32[w][tid] = x;
                    x += c;
                }
                subOff[s][tid] = (uint16_t)x;
            }
            __syncthreads();

            posR[s] = valid ? (waveCnt32[wv][d] + rank) : 0u;
            __syncthreads();
        }

        if (tid < 256) {
            uint32_t run = 0;
            #pragma unroll
            for (int s = 0; s < NSUB; ++s) {
                uint32_t c = subOff[s][tid];
                subOff[s][tid] = (uint16_t)run;
                run += c;
            }
            tileCnt[tid] = run;
            scanb[tid] = run;
        }
        __syncthreads();
        for (int off = 1; off < 256; off <<= 1) {
            uint32_t add = 0;
            if (tid < 256 && tid >= off) add = scanb[tid - off];
            __syncthreads();
            if (tid < 256) scanb[tid] += add;
            __syncthreads();
        }
        if (tid < 256) tileStart[tid] = (tid == 0) ? 0u : scanb[tid - 1];
        __syncthreads();

        #pragma unroll
        for (int s = 0; s < NSUB; ++s) {
            const int i = tbase + s * BLK + tid;
            if (i < N) {
                const uint32_t d = (keyR[s] >> SHIFT) & 255u;
                const uint32_t pos = tileStart[d] + (uint32_t)subOff[s][d] + posR[s];
                stageKey[pos] = keyR[s];
                stageIdx[pos] = (uint16_t)(FIRST ? (uint32_t)i : idxR[s]);
            }
        }
        __syncthreads();

        for (int p = tid; p < tileLen; p += BLK) {
            const uint32_t k = stageKey[p];
            const uint32_t d = (k >> SHIFT) & 255u;
            const uint32_t g = cursor[d] + (uint32_t)p - tileStart[d];
            if (LAST) {
                outIdx[base + g] = (uint32_t)stageIdx[p];
                outW[base + g]   = __uint_as_float(~k);
            } else {
                keyDst[base + g] = k;
                idxDst[base + g] = stageIdx[p];
            }
        }
        __syncthreads();
        if (tid < 256) cursor[tid] += tileCnt[tid];
        __syncthreads();
    }
}

// ---------------------------------------------------------------------------
// TIER C (round-1 proven): gather-based fallback, no workspace.
// ---------------------------------------------------------------------------
template <int SHIFT>
__global__ __launch_bounds__(BLK) void radix_pass_fb(const float* __restrict__ wts,
                                                     const uint32_t* __restrict__ src,
                                                     uint32_t* __restrict__ dst) {
    __shared__ uint32_t hist[256];
    __shared__ uint32_t scanb[256];
    __shared__ uint32_t running[256];
    __shared__ uint32_t waveCnt32[NWAVE][256];

    const int row = blockIdx.x;
    const size_t base = (size_t)row * N;
    const int tid  = threadIdx.x;
    const int lane = tid & 63;
    const int wv   = tid >> 6;

    if (tid < 256) hist[tid] = 0;
    __syncthreads();
    for (int i = tid; i < N; i += BLK) {
        uint32_t idx = (SHIFT == 0) ? (uint32_t)i : src[base + i];
        uint32_t d = (sort_key(wts[base + idx]) >> SHIFT) & 255u;
        atomicAdd(&hist[d], 1u);
    }
    __syncthreads();

    if (tid < 256) scanb[tid] = hist[tid];
    __syncthreads();
    for (int off = 1; off < 256; off <<= 1) {
        uint32_t add = 0;
        if (tid < 256 && tid >= off) add = scanb[tid - off];
        __syncthreads();
        if (tid < 256) scanb[tid] += add;
        __syncthreads();
    }
    if (tid < 256) running[tid] = (tid == 0) ? 0u : scanb[tid - 1];
    __syncthreads();

    const int numTiles = (N + BLK - 1) / BLK;
    for (int t = 0; t < numTiles; ++t) {
        for (int j = tid; j < NWAVE * 256; j += BLK) ((uint32_t*)waveCnt32)[j] = 0;
        __syncthreads();

        const int i = t * BLK + tid;
        const bool valid = (i < N);
        uint32_t idx = 0, d = 0;
        if (valid) {
            idx = (SHIFT == 0) ? (uint32_t)i : src[base + i];
            d = (sort_key(wts[base + idx]) >> SHIFT) & 255u;
        }
        unsigned long long peers = __ballot(valid);
        #pragma unroll
        for (int b = 0; b < 8; ++b) {
            unsigned long long bit = __ballot(valid && ((d >> b) & 1u));
            peers &= ((d >> b) & 1u) ? bit : ~bit;
        }
        const unsigned long long lower = peers & ((1ull << lane) - 1ull);
        const uint32_t rank = (uint32_t)__popcll(lower);
        if (valid && lower == 0ull) waveCnt32[wv][d] = (uint32_t)__popcll(peers);
        __syncthreads();

        if (tid < 256) {
            uint32_t s = running[tid];
            #pragma unroll
            for (int w = 0; w < NWAVE; ++w) {
                uint32_t c = waveCnt32[w][tid];
                waveCnt32[w][tid] = s;
                s += c;
            }
            running[tid] = s;
        }
        __syncthreads();

        if (valid) {
            uint32_t pos = waveCnt32[wv][d] + rank;
            dst[base + pos] = idx;
        }
        __syncthreads();
    }
}

__global__ __launch_bounds__(BLK) void finalize_fb(const float* __restrict__ wts,
                                                   const uint32_t* __restrict__ sidx,
                                                   float* __restrict__ out0,
                                                   float* __restrict__ out1,
                                                   float* __restrict__ out2) {
    __shared__ float waveSum[NWAVE];
    __shared__ int   waveFirst[NWAVE];
    __shared__ float waveCum[NWAVE];
    __shared__ int   s_k;
    __shared__ float s_total;

    const int row = blockIdx.x;
    const size_t base = (size_t)row * N;
    const int tid  = threadIdx.x;
    const int lane = tid & 63;
    const int wv   = tid >> 6;

    if (tid == 0) { s_k = -1; s_total = 0.f; }
    __syncthreads();

    float carry = 0.f;
    const int numTiles = (N + BLK - 1) / BLK;
    for (int t = 0; t < numTiles; ++t) {
        const int i = t * BLK + tid;
        const bool valid = (i < N);
        float w = valid ? wts[base + sidx[base + i]] : 0.f;

        float s = w;
        #pragma unroll
        for (int o = 1; o < 64; o <<= 1) {
            float u = __shfl_up(s, o);
            if (lane >= o) s += u;
        }
        if (lane == 63) waveSum[wv] = s;
        __syncthreads();

        float prefix = 0.f, blockTot = 0.f;
        #pragma unroll
        for (int w2 = 0; w2 < NWAVE; ++w2) {
            float t2 = waveSum[w2];
            if (w2 < wv) prefix += t2;
            blockTot += t2;
        }
        const float cum = carry + prefix + s;

        const bool exceed = valid && (cum > THRESH);
        const unsigned long long bal = __ballot(exceed);
        const int fl = (bal == 0ull) ? 64 : (__ffsll(bal) - 1);
        if (lane == 0) waveFirst[wv] = fl;
        if (fl < 64 && lane == fl) waveCum[wv] = cum;
        __syncthreads();
        if (tid == 0) {
            for (int w2 = 0; w2 < NWAVE; ++w2) {
                if (waveFirst[w2] < 64) {
                    s_k = t * BLK + w2 * 64 + waveFirst[w2] + 1;
                    s_total = waveCum[w2];
                    break;
                }
            }
        }
        __syncthreads();
        if (s_k >= 0) break;
        carry += blockTot;
        __syncthreads();
    }

    int k = s_k;
    float total = s_total;
    if (k < 0) { k = N; total = carry; }

    for (int i = tid; i < N; i += BLK) {
        const uint32_t idx = sidx[base + i];
        const float w = wts[base + idx];
        out0[base + i] = (float)idx;
        out1[base + i] = (i < k) ? (w / total) : 0.f;
    }
    if (tid == 0) out2[row] = (float)k;
}

// ---------------------------------------------------------------------------

extern "C" void kernel_launch(void* const* d_in, const int* in_sizes, int n_in,
                              void* d_out, int out_size, void* d_ws, size_t ws_size,
                              hipStream_t stream) {
    const float* wts = (const float*)d_in[0];
    float* out0 = (float*)d_out;                       // sorted_idx (as f32)
    float* out1 = out0 + (size_t)B * N;                // norm_w
    float* out2 = out0 + 2 * (size_t)B * N;            // k (as f32)

    const size_t PAIR_BYTES = (size_t)B * N * 8;       // 205,852,672
    const size_t KEY_BYTES  = (size_t)B * N * 4;
    const size_t IDX_BYTES  = (size_t)B * N * 2;
    const size_t HIST_BYTES = (size_t)B * 4 * 256 * 4; // 2,097,152
    const size_t SEG_BYTES  = (size_t)4 * B * 256 * 4; // 2,097,152 (4 pass slots)
    const size_t WS_A = PAIR_BYTES + HIST_BYTES + SEG_BYTES;
    const size_t WS_B = KEY_BYTES + IDX_BYTES + HIST_BYTES + SEG_BYTES;

    dim3 g(B), b(BLK);
    if (ws_size >= WS_A) {
        // Tier A: segmented pipelined packed-u64 path (4 blocks/CU).
        uint8_t* ws = (uint8_t*)d_ws;
        unsigned long long* pairWS  = (unsigned long long*)ws;
        uint32_t*           histWS  = (uint32_t*)(ws + PAIR_BYTES);
        uint32_t*           segCnt  = (uint32_t*)(ws + PAIR_BYTES + HIST_BYTES);
        unsigned long long* pairOUT = (unsigned long long*)d_out;  // 206MB in d_out
        uint32_t* seg0 = segCnt;                    // pass1 (from hist4, overwritten)
        uint32_t* seg1 = segCnt + (size_t)B * 256;  // pass2 (accumulated)
        uint32_t* seg2 = segCnt + 2 * (size_t)B * 256;
        uint32_t* seg3 = segCnt + 3 * (size_t)B * 256;

        // zero the accumulated slots (pass2..4 inputs)
        hipMemsetAsync(seg1, 0, 3 * (size_t)B * 256 * 4, stream);

        dim3 g2(B, 2);
        hist4_fast<<<g, b, 0, stream>>>(wts, histWS, seg0);
        scatter_seg<0,  true,  false><<<g2, b, 0, stream>>>(wts, nullptr, pairWS, nullptr, nullptr, histWS, seg0, seg1);
        scatter_seg<8,  false, false><<<g2, b, 0, stream>>>(nullptr, pairWS, pairOUT, nullptr, nullptr, histWS, seg1, seg2);
        scatter_seg<16, false, false><<<g2, b, 0, stream>>>(nullptr, pairOUT, pairWS, nullptr, nullptr, histWS, seg2, seg3);
        scatter_seg<24, false, true ><<<g2, b, 0, stream>>>(nullptr, pairWS, nullptr, (uint32_t*)out0, out1, histWS, seg3, nullptr);
        finalize_row<<<g, b, 0, stream>>>(out0, out1, out2);
    } else if (ws_size >= WS_B) {
        // Tier B: round-3 proven path (+ fast hist & merged finalize).
        uint8_t* ws = (uint8_t*)d_ws;
        uint32_t* keyWS  = (uint32_t*)ws;
        uint16_t* idxWS  = (uint16_t*)(ws + KEY_BYTES);
        uint32_t* histWS = (uint32_t*)(ws + KEY_BYTES + IDX_BYTES);
        uint32_t* segWS  = (uint32_t*)(ws + KEY_BYTES + IDX_BYTES + HIST_BYTES);
        uint32_t* keyOUT = (uint32_t*)out0;
        uint16_t* idxOUT = (uint16_t*)out1;

        hist4_fast<<<g, b, 0, stream>>>(wts, histWS, segWS);
        scatter_tile<0,  true,  false><<<g, b, 0, stream>>>(wts, nullptr, nullptr, keyWS, idxWS, nullptr, nullptr, histWS);
        scatter_tile<8,  false, false><<<g, b, 0, stream>>>(wts, keyWS, idxWS, keyOUT, idxOUT, nullptr, nullptr, histWS);
        scatter_tile<16, false, false><<<g, b, 0, stream>>>(wts, keyOUT, idxOUT, keyWS, idxWS, nullptr, nullptr, histWS);
        scatter_tile<24, false, true ><<<g, b, 0, stream>>>(wts, keyWS, idxWS, nullptr, nullptr, (uint32_t*)out0, out1, histWS);
        finalize_row<<<g, b, 0, stream>>>(out0, out1, out2);
    } else {
        // Tier C: no-workspace fallback.
        uint32_t* bufA = (uint32_t*)out0;
        uint32_t* bufB = (uint32_t*)out1;
        radix_pass_fb<0 ><<<g, b, 0, stream>>>(wts, nullptr, bufA);
        radix_pass_fb<8 ><<<g, b, 0, stream>>>(wts, bufA, bufB);
        radix_pass_fb<16><<<g, b, 0, stream>>>(wts, bufB, bufA);
        radix_pass_fb<24><<<g, b, 0, stream>>>(wts, bufA, bufB);
        finalize_fb<<<g, b, 0, stream>>>(wts, bufB, out0, out1, out2);
    }
}

// Round 10
// 636.903 us; speedup vs baseline: 1.1650x; 1.1650x over previous
//
#include <hip/hip_runtime.h>
#include <stdint.h>

#define B    512
#define N    50257
#define BLK  512
#define NWAVE 8
#define TILE 8192
#define CHUNK 1024           // per-wave contiguous chunk = TILE/NWAVE
#define NGRP 16              // 64-elem groups per chunk
#define THRESH 0.4f

// Softmax weights are strictly positive floats: raw bit pattern is monotone
// in value. Complement -> ascending stable order == descending weight order,
// ties broken by ascending original index (stable LSD radix), matching
// jnp.argsort(-weights).
__device__ __forceinline__ uint32_t sort_key(float w) { return ~__float_as_uint(w); }

__device__ __forceinline__ void hist_elem(uint32_t* hw0, const float w) {
    const uint32_t key = sort_key(w);
    atomicAdd(hw0 + (key & 255u), 1u);
    atomicAdd(hw0 + 256 + ((key >> 8) & 255u), 1u);
    atomicAdd(hw0 + 512 + ((key >> 16) & 255u), 1u);
    atomicAdd(hw0 + 768 + ((key >> 24) & 255u), 1u);
}

// ---------------------------------------------------------------------------
// Histogram kernel (per-wave-private bins, plain LDS atomics, float4 sweep).
// ---------------------------------------------------------------------------
__global__ __launch_bounds__(BLK) void hist4_fast(const float* __restrict__ wts,
                                                  uint32_t* __restrict__ histWS) {
    __shared__ uint32_t hw[NWAVE][4][256];   // 32 KB
    __shared__ uint32_t wtot[4];
    const int row = blockIdx.x;
    const size_t base = (size_t)row * N;
    const int tid = threadIdx.x;
    const int lane = tid & 63;
    const int wv = tid >> 6;

    {   // zero own wave's slice (no cross-wave access -> no barrier needed)
        uint32_t* p = &hw[wv][0][0];
        for (int j = lane; j < 4 * 256; j += 64) p[j] = 0;
    }
    uint32_t* hw0 = &hw[wv][0][0];

    // vectorized sweep (order-independent): head to 16B alignment, f4 body, tail
    const int head = (int)((4 - (base & 3)) & 3);
    for (int i = tid; i < head; i += BLK) hist_elem(hw0, wts[base + i]);
    const int nvec = (N - head) >> 2;
    const float4* v4 = (const float4*)(wts + base + head);
    for (int iv = tid; iv < nvec; iv += BLK) {
        const float4 f = v4[iv];
        hist_elem(hw0, f.x); hist_elem(hw0, f.y);
        hist_elem(hw0, f.z); hist_elem(hw0, f.w);
    }
    for (int i = head + 4 * nvec + tid; i < N; i += BLK) hist_elem(hw0, wts[base + i]);
    __syncthreads();

    for (int p = 0; p < 4; ++p) {
        uint32_t cnt = 0;
        if (tid < 256) {
            #pragma unroll
            for (int w = 0; w < NWAVE; ++w) cnt += hw[w][p][tid];
        }
        // exclusive scan over 256 bins: intra-wave shfl + cross-wave via wtot
        uint32_t incl = cnt;
        #pragma unroll
        for (int o = 1; o < 64; o <<= 1) {
            const uint32_t u = __shfl_up(incl, o);
            if (lane >= o) incl += u;
        }
        if (tid < 256 && lane == 63) wtot[tid >> 6] = incl;
        __syncthreads();
        if (tid < 256) {
            uint32_t prefix = 0;
            const int w4 = tid >> 6;
            #pragma unroll
            for (int w2 = 0; w2 < 4; ++w2) if (w2 < w4) prefix += wtot[w2];
            histWS[((size_t)row * 4 + p) * 256 + tid] = prefix + incl - cnt;
        }
        __syncthreads();   // protect wtot reuse
    }
}

// ---------------------------------------------------------------------------
// TIER A: r5-proven pipelined wave-private scatter; global payload is SPLIT
// into key (u32) + idx (u16) streams (6 B/elem vs 8). LDS staging/ranking
// stays u64 (unchanged machinery). TILE=8192, grid=B (1 block/row, 2/CU) —
// the proven regime; r9 showed more blocks thrash L2/L3 reuse.
// Prefetch issues AFTER the layout barrier (r5 spot; earlier broke L3 reuse).
// ---------------------------------------------------------------------------
template <int SHIFT, bool FIRST, bool LAST>
__global__ __launch_bounds__(BLK, 4) void scatter_pl(const float* __restrict__ wts,
                                                     const uint32_t* __restrict__ keySrc,
                                                     const uint16_t* __restrict__ idxSrc,
                                                     uint32_t* __restrict__ keyDst,
                                                     uint16_t* __restrict__ idxDst,
                                                     uint32_t* __restrict__ outIdx,
                                                     float* __restrict__ outW,
                                                     const uint32_t* __restrict__ histWS) {
    __shared__ __align__(16) unsigned long long stage[TILE];  // 64 KB
    __shared__ uint32_t waveCnt[NWAVE][256];                  //  8 KB
    __shared__ uint32_t delta[256];                           //  1 KB
    __shared__ uint32_t wtot[4];

    const int row = blockIdx.x;
    const size_t base = (size_t)row * N;
    const int tid  = threadIdx.x;
    const int lane = tid & 63;
    const int wv   = tid >> 6;
    constexpr int PASS = SHIFT / 8;
    constexpr int KS = SHIFT + 16;   // digit position within packed pair

    uint32_t curReg = 0;             // this thread's bucket cursor (tid<256)
    if (tid < 256) curReg = histWS[((size_t)row * 4 + PASS) * 256 + tid];

    const int numTiles = (N + TILE - 1) / TILE;   // 7

    unsigned long long pairN[NGRP];
    {   // prefetch tile 0 (always full: TILE < N)
        const int cb = wv * CHUNK;
        #pragma unroll
        for (int g = 0; g < NGRP; ++g) {
            const int i = cb + g * 64 + lane;
            pairN[g] = FIRST ? (((unsigned long long)sort_key(wts[base + i]) << 16) | (uint32_t)i)
                             : (((unsigned long long)keySrc[base + i] << 16) | (uint32_t)idxSrc[base + i]);
        }
    }

    for (int t = 0; t < numTiles; ++t) {
        const int tbase = t * TILE;
        const int tileLen = (N - tbase < TILE) ? (N - tbase) : TILE;
        const int cbase = tbase + wv * CHUNK;
        const bool full = (tbase + TILE <= N);

        // ---- Phase 1: rank own chunk from registers (NO barriers) ----
        // Safe to zero own waveCnt row here: phase 2 of tile t-1 finished
        // reading all rows before barrier (C,t-1) < (D,t-1).
        {
            uint4* z = (uint4*)&waveCnt[wv][0];
            z[lane] = make_uint4(0u, 0u, 0u, 0u);
        }
        unsigned long long pairR[NGRP];
        uint32_t posR[NGRP];
        #pragma unroll
        for (int g = 0; g < NGRP; ++g) pairR[g] = pairN[g];

        if (full) {
            #pragma unroll
            for (int g = 0; g < NGRP; ++g) {
                const uint32_t d = (uint32_t)(pairR[g] >> KS) & 255u;
                unsigned long long peers = ~0ull;
                #pragma unroll
                for (int bb = 0; bb < 8; ++bb) {
                    const unsigned long long bit = __ballot((d >> bb) & 1u);
                    peers &= ((d >> bb) & 1u) ? bit : ~bit;
                }
                const unsigned long long lower = peers & ((1ull << lane) - 1ull);
                const uint32_t cnt = waveCnt[wv][d];
                posR[g] = cnt + (uint32_t)__popcll(lower);
                if (lower == 0ull) waveCnt[wv][d] = cnt + (uint32_t)__popcll(peers);
            }
        } else {
            #pragma unroll
            for (int g = 0; g < NGRP; ++g) {
                const int i = cbase + g * 64 + lane;
                const bool valid = (i < N);
                const uint32_t d = (uint32_t)(pairR[g] >> KS) & 255u;
                unsigned long long peers = __ballot(valid);
                #pragma unroll
                for (int bb = 0; bb < 8; ++bb) {
                    const unsigned long long bit = __ballot((d >> bb) & 1u);
                    peers &= ((d >> bb) & 1u) ? bit : ~bit;
                }
                const unsigned long long lower = peers & ((1ull << lane) - 1ull);
                uint32_t cnt = 0;
                if (valid) cnt = waveCnt[wv][d];
                posR[g] = cnt + (uint32_t)__popcll(lower);
                if (valid && lower == 0ull) waveCnt[wv][d] = cnt + (uint32_t)__popcll(peers);
            }
        }
        __syncthreads();                               // (A) ranks done; stage(t-1) drained

        // ---- Phase 2: tile layout (shfl scan, 2 barriers) ----
        uint32_t run = 0;
        if (tid < 256) {
            #pragma unroll
            for (int w = 0; w < NWAVE; ++w) {
                const uint32_t c = waveCnt[w][tid];
                waveCnt[w][tid] = run;                 // excl offset across waves
                run += c;
            }
        }
        uint32_t incl = run;
        #pragma unroll
        for (int o = 1; o < 64; o <<= 1) {
            const uint32_t u = __shfl_up(incl, o);
            if (lane >= o) incl += u;
        }
        if (tid < 256 && lane == 63) wtot[tid >> 6] = incl;
        __syncthreads();                               // (B)
        if (tid < 256) {
            uint32_t prefix = 0;
            const int w4 = tid >> 6;
            #pragma unroll
            for (int w2 = 0; w2 < 4; ++w2) if (w2 < w4) prefix += wtot[w2];
            const uint32_t ts = prefix + incl - run;   // tileStart[tid]
            delta[tid] = curReg - ts;                  // global = delta[d] + p
            curReg += run;
            #pragma unroll
            for (int w = 0; w < NWAVE; ++w) waveCnt[w][tid] += ts;
        }
        __syncthreads();                               // (C) layout ready

        // ---- Prefetch next tile (latency hides under phases 3-4; r5 spot) ----
        if (t + 1 < numTiles) {
            const int ncb = (t + 1) * TILE + wv * CHUNK;
            if (ncb + CHUNK <= N) {                    // wave-uniform branch
                #pragma unroll
                for (int g = 0; g < NGRP; ++g) {
                    const int i = ncb + g * 64 + lane;
                    pairN[g] = FIRST ? (((unsigned long long)sort_key(wts[base + i]) << 16) | (uint32_t)i)
                                     : (((unsigned long long)keySrc[base + i] << 16) | (uint32_t)idxSrc[base + i]);
                }
            } else {
                #pragma unroll
                for (int g = 0; g < NGRP; ++g) {
                    const int i = ncb + g * 64 + lane;
                    unsigned long long pair = 0;
                    if (i < N)
                        pair = FIRST ? (((unsigned long long)sort_key(wts[base + i]) << 16) | (uint32_t)i)
                                     : (((unsigned long long)keySrc[base + i] << 16) | (uint32_t)idxSrc[base + i]);
                    pairN[g] = pair;
                }
            }
        }

        // ---- Phase 3: stage bucket-contiguous in LDS ----
        if (full) {
            #pragma unroll
            for (int g = 0; g < NGRP; ++g) {
                const uint32_t d = (uint32_t)(pairR[g] >> KS) & 255u;
                stage[waveCnt[wv][d] + posR[g]] = pairR[g];
            }
        } else {
            #pragma unroll
            for (int g = 0; g < NGRP; ++g) {
                const int i = cbase + g * 64 + lane;
                if (i < N) {
                    const uint32_t d = (uint32_t)(pairR[g] >> KS) & 255u;
                    stage[waveCnt[wv][d] + posR[g]] = pairR[g];
                }
            }
        }
        __syncthreads();                               // (D) stage complete

        // ---- Phase 4: 2-wide flush to SPLIT key/idx streams ----
        const int tileLenEven = tileLen & ~1;
        for (int p0 = 2 * tid; p0 < tileLenEven; p0 += 2 * BLK) {
            const ulonglong2 two = *(const ulonglong2*)&stage[p0];   // 16B aligned
            const uint32_t d0 = (uint32_t)(two.x >> KS) & 255u;
            const uint32_t d1 = (uint32_t)(two.y >> KS) & 255u;
            const uint32_t g0 = delta[d0] + (uint32_t)p0;
            const uint32_t g1 = delta[d1] + (uint32_t)p0 + 1u;
            if (LAST) {
                outIdx[base + g0] = (uint32_t)(two.x & 0xFFFFull);
                outW[base + g0]   = __uint_as_float(~(uint32_t)(two.x >> 16));
                outIdx[base + g1] = (uint32_t)(two.y & 0xFFFFull);
                outW[base + g1]   = __uint_as_float(~(uint32_t)(two.y >> 16));
            } else {
                keyDst[base + g0] = (uint32_t)(two.x >> 16);
                idxDst[base + g0] = (uint16_t)(two.x & 0xFFFFull);
                keyDst[base + g1] = (uint32_t)(two.y >> 16);
                idxDst[base + g1] = (uint16_t)(two.y & 0xFFFFull);
            }
        }
        for (int p = tileLenEven + tid; p < tileLen; p += BLK) {     // odd tail
            const unsigned long long pair = stage[p];
            const uint32_t d = (uint32_t)(pair >> KS) & 255u;
            const uint32_t g = delta[d] + (uint32_t)p;
            if (LAST) {
                outIdx[base + g] = (uint32_t)(pair & 0xFFFFull);
                outW[base + g]   = __uint_as_float(~(uint32_t)(pair >> 16));
            } else {
                keyDst[base + g] = (uint32_t)(pair >> 16);
                idxDst[base + g] = (uint16_t)(pair & 0xFFFFull);
            }
        }
        // no trailing barrier: (A) of the next tile separates flush(t) reads
        // from stage(t+1) writes and delta(t+1) updates.
    }
}

// ---------------------------------------------------------------------------
// Merged scan + normalize + idx->float (in place), block per row.
// out0 holds u32 idx, out1 holds sorted w on entry.
// ---------------------------------------------------------------------------
__global__ __launch_bounds__(BLK) void finalize_row(float* __restrict__ out0,
                                                    float* __restrict__ out1,
                                                    float* __restrict__ out2) {
    __shared__ float waveSum[NWAVE];
    __shared__ int   waveFirst[NWAVE];
    __shared__ float waveCum[NWAVE];
    __shared__ int   s_k;
    __shared__ float s_total;

    const int row = blockIdx.x;
    const size_t base = (size_t)row * N;
    const int tid  = threadIdx.x;
    const int lane = tid & 63;
    const int wv   = tid >> 6;

    if (tid == 0) { s_k = -1; s_total = 0.f; }
    __syncthreads();

    // Phase A: block-wide running cumsum with early exit
    float carry = 0.f;
    const int numTiles = (N + BLK - 1) / BLK;
    for (int t = 0; t < numTiles; ++t) {
        const int i = t * BLK + tid;
        const bool valid = (i < N);
        float w = valid ? out1[base + i] : 0.f;

        float s = w;
        #pragma unroll
        for (int o = 1; o < 64; o <<= 1) {
            float u = __shfl_up(s, o);
            if (lane >= o) s += u;
        }
        if (lane == 63) waveSum[wv] = s;
        __syncthreads();

        float prefix = 0.f, blockTot = 0.f;
        #pragma unroll
        for (int w2 = 0; w2 < NWAVE; ++w2) {
            float t2 = waveSum[w2];
            if (w2 < wv) prefix += t2;
            blockTot += t2;
        }
        const float cum = carry + prefix + s;

        const bool exceed = valid && (cum > THRESH);
        const unsigned long long bal = __ballot(exceed);
        const int fl = (bal == 0ull) ? 64 : (__ffsll(bal) - 1);
        if (lane == 0) waveFirst[wv] = fl;
        if (fl < 64 && lane == fl) waveCum[wv] = cum;
        __syncthreads();
        if (tid == 0) {
            for (int w2 = 0; w2 < NWAVE; ++w2) {
                if (waveFirst[w2] < 64) {
                    s_k = t * BLK + w2 * 64 + waveFirst[w2] + 1;
                    s_total = waveCum[w2];
                    break;
                }
            }
        }
        __syncthreads();
        if (s_k >= 0) break;
        carry += blockTot;
        __syncthreads();
    }

    int k = s_k;
    float total = s_total;
    if (k < 0) { k = N; total = carry; }
    const float inv = 1.0f / total;

    // Phase B: in-place convert + normalize, vectorized 16B (per-thread
    // read-before-write on identical addresses -> safe).
    const uint32_t* idxU = (const uint32_t*)out0;
    const int head = (int)((4 - (base & 3)) & 3);     // to 16B alignment
    const int nvec = (N - head) >> 2;
    const int vend = head + 4 * nvec;

    for (int i = tid; i < head; i += BLK) {           // head (<4 elems)
        const uint32_t idx = idxU[base + i];
        const float w = out1[base + i];
        out0[base + i] = (float)idx;
        out1[base + i] = (i < k) ? (w * inv) : 0.f;
    }
    const uint4*  ivp = (const uint4*)(idxU + base + head);
    float4*       o0v = (float4*)(out0 + base + head);
    float4*       o1v = (float4*)(out1 + base + head);
    for (int v = tid; v < nvec; v += BLK) {
        const uint4  iv = ivp[v];
        const float4 wv4 = o1v[v];
        const int i = head + 4 * v;
        float4 o0, o1;
        o0.x = (float)iv.x; o0.y = (float)iv.y; o0.z = (float)iv.z; o0.w = (float)iv.w;
        o1.x = (i + 0 < k) ? wv4.x * inv : 0.f;
        o1.y = (i + 1 < k) ? wv4.y * inv : 0.f;
        o1.z = (i + 2 < k) ? wv4.z * inv : 0.f;
        o1.w = (i + 3 < k) ? wv4.w * inv : 0.f;
        o0v[v] = o0;
        o1v[v] = o1;
    }
    for (int i = vend + tid; i < N; i += BLK) {       // tail (<4 elems)
        const uint32_t idx = idxU[base + i];
        const float w = out1[base + i];
        out0[base + i] = (float)idx;
        out1[base + i] = (i < k) ? (w * inv) : 0.f;
    }
    if (tid == 0) out2[row] = (float)k;
}

// ---------------------------------------------------------------------------
// FALLBACK (round-1 proven): gather-based, no workspace.
// ---------------------------------------------------------------------------
template <int SHIFT>
__global__ __launch_bounds__(BLK) void radix_pass_fb(const float* __restrict__ wts,
                                                     const uint32_t* __restrict__ src,
                                                     uint32_t* __restrict__ dst) {
    __shared__ uint32_t hist[256];
    __shared__ uint32_t scanb[256];
    __shared__ uint32_t running[256];
    __shared__ uint32_t waveCnt32[NWAVE][256];

    const int row = blockIdx.x;
    const size_t base = (size_t)row * N;
    const int tid  = threadIdx.x;
    const int lane = tid & 63;
    const int wv   = tid >> 6;

    if (tid < 256) hist[tid] = 0;
    __syncthreads();
    for (int i = tid; i < N; i += BLK) {
        uint32_t idx = (SHIFT == 0) ? (uint32_t)i : src[base + i];
        uint32_t d = (sort_key(wts[base + idx]) >> SHIFT) & 255u;
        atomicAdd(&hist[d], 1u);
    }
    __syncthreads();

    if (tid < 256) scanb[tid] = hist[tid];
    __syncthreads();
    for (int off = 1; off < 256; off <<= 1) {
        uint32_t add = 0;
        if (tid < 256 && tid >= off) add = scanb[tid - off];
        __syncthreads();
        if (tid < 256) scanb[tid] += add;
        __syncthreads();
    }
    if (tid < 256) running[tid] = (tid == 0) ? 0u : scanb[tid - 1];
    __syncthreads();

    const int numTiles = (N + BLK - 1) / BLK;
    for (int t = 0; t < numTiles; ++t) {
        for (int j = tid; j < NWAVE * 256; j += BLK) ((uint32_t*)waveCnt32)[j] = 0;
        __syncthreads();

        const int i = t * BLK + tid;
        const bool valid = (i < N);
        uint32_t idx = 0, d = 0;
        if (valid) {
            idx = (SHIFT == 0) ? (uint32_t)i : src[base + i];
            d = (sort_key(wts[base + idx]) >> SHIFT) & 255u;
        }
        unsigned long long peers = __ballot(valid);
        #pragma unroll
        for (int b = 0; b < 8; ++b) {
            unsigned long long bit = __ballot(valid && ((d >> b) & 1u));
            peers &= ((d >> b) & 1u) ? bit : ~bit;
        }
        const unsigned long long lower = peers & ((1ull << lane) - 1ull);
        const uint32_t rank = (uint32_t)__popcll(lower);
        if (valid && lower == 0ull) waveCnt32[wv][d] = (uint32_t)__popcll(peers);
        __syncthreads();

        if (tid < 256) {
            uint32_t s = running[tid];
            #pragma unroll
            for (int w = 0; w < NWAVE; ++w) {
                uint32_t c = waveCnt32[w][tid];
                waveCnt32[w][tid] = s;
                s += c;
            }
            running[tid] = s;
        }
        __syncthreads();

        if (valid) {
            uint32_t pos = waveCnt32[wv][d] + rank;
            dst[base + pos] = idx;
        }
        __syncthreads();
    }
}

__global__ __launch_bounds__(BLK) void finalize_fb(const float* __restrict__ wts,
                                                   const uint32_t* __restrict__ sidx,
                                                   float* __restrict__ out0,
                                                   float* __restrict__ out1,
                                                   float* __restrict__ out2) {
    __shared__ float waveSum[NWAVE];
    __shared__ int   waveFirst[NWAVE];
    __shared__ float waveCum[NWAVE];
    __shared__ int   s_k;
    __shared__ float s_total;

    const int row = blockIdx.x;
    const size_t base = (size_t)row * N;
    const int tid  = threadIdx.x;
    const int lane = tid & 63;
    const int wv   = tid >> 6;

    if (tid == 0) { s_k = -1; s_total = 0.f; }
    __syncthreads();

    float carry = 0.f;
    const int numTiles = (N + BLK - 1) / BLK;
    for (int t = 0; t < numTiles; ++t) {
        const int i = t * BLK + tid;
        const bool valid = (i < N);
        float w = valid ? wts[base + sidx[base + i]] : 0.f;

        float s = w;
        #pragma unroll
        for (int o = 1; o < 64; o <<= 1) {
            float u = __shfl_up(s, o);
            if (lane >= o) s += u;
        }
        if (lane == 63) waveSum[wv] = s;
        __syncthreads();

        float prefix = 0.f, blockTot = 0.f;
        #pragma unroll
        for (int w2 = 0; w2 < NWAVE; ++w2) {
            float t2 = waveSum[w2];
            if (w2 < wv) prefix += t2;
            blockTot += t2;
        }
        const float cum = carry + prefix + s;

        const bool exceed = valid && (cum > THRESH);
        const unsigned long long bal = __ballot(exceed);
        const int fl = (bal == 0ull) ? 64 : (__ffsll(bal) - 1);
        if (lane == 0) waveFirst[wv] = fl;
        if (fl < 64 && lane == fl) waveCum[wv] = cum;
        __syncthreads();
        if (tid == 0) {
            for (int w2 = 0; w2 < NWAVE; ++w2) {
                if (waveFirst[w2] < 64) {
                    s_k = t * BLK + w2 * 64 + waveFirst[w2] + 1;
                    s_total = waveCum[w2];
                    break;
                }
            }
        }
        __syncthreads();
        if (s_k >= 0) break;
        carry += blockTot;
        __syncthreads();
    }

    int k = s_k;
    float total = s_total;
    if (k < 0) { k = N; total = carry; }

    for (int i = tid; i < N; i += BLK) {
        const uint32_t idx = sidx[base + i];
        const float w = wts[base + idx];
        out0[base + i] = (float)idx;
        out1[base + i] = (i < k) ? (w / total) : 0.f;
    }
    if (tid == 0) out2[row] = (float)k;
}

// ---------------------------------------------------------------------------

extern "C" void kernel_launch(void* const* d_in, const int* in_sizes, int n_in,
                              void* d_out, int out_size, void* d_ws, size_t ws_size,
                              hipStream_t stream) {
    const float* wts = (const float*)d_in[0];
    float* out0 = (float*)d_out;                       // sorted_idx (as f32)
    float* out1 = out0 + (size_t)B * N;                // norm_w
    float* out2 = out0 + 2 * (size_t)B * N;            // k (as f32)

    const size_t KEY_BYTES  = (size_t)B * N * 4;       // 102,926,336
    const size_t IDX_BYTES  = (size_t)B * N * 2;       //  51,463,168
    const size_t HIST_BYTES = (size_t)B * 4 * 256 * 4; //   2,097,152
    const size_t WS_NEED = KEY_BYTES + IDX_BYTES + HIST_BYTES;

    dim3 g(B), b(BLK);
    if (ws_size >= WS_NEED) {
        // Tier A: pipelined wave-private path, 6-byte split payload.
        // Ping-pong: buffer A = {keyWS, idxWS} in d_ws; buffer B = {key in
        // out0 region, idx in out1 region} of d_out.
        uint8_t* ws = (uint8_t*)d_ws;
        uint32_t* keyWS  = (uint32_t*)ws;
        uint16_t* idxWS  = (uint16_t*)(ws + KEY_BYTES);
        uint32_t* histWS = (uint32_t*)(ws + KEY_BYTES + IDX_BYTES);
        uint32_t* keyOUT = (uint32_t*)out0;
        uint16_t* idxOUT = (uint16_t*)out1;

        hist4_fast<<<g, b, 0, stream>>>(wts, histWS);
        scatter_pl<0,  true,  false><<<g, b, 0, stream>>>(wts, nullptr, nullptr, keyWS, idxWS, nullptr, nullptr, histWS);
        scatter_pl<8,  false, false><<<g, b, 0, stream>>>(nullptr, keyWS, idxWS, keyOUT, idxOUT, nullptr, nullptr, histWS);
        scatter_pl<16, false, false><<<g, b, 0, stream>>>(nullptr, keyOUT, idxOUT, keyWS, idxWS, nullptr, nullptr, histWS);
        scatter_pl<24, false, true ><<<g, b, 0, stream>>>(nullptr, keyWS, idxWS, nullptr, nullptr, (uint32_t*)out0, out1, histWS);
        finalize_row<<<g, b, 0, stream>>>(out0, out1, out2);
    } else {
        // Fallback: no-workspace gather path (round-1 proven).
        uint32_t* bufA = (uint32_t*)out0;
        uint32_t* bufB = (uint32_t*)out1;
        radix_pass_fb<0 ><<<g, b, 0, stream>>>(wts, nullptr, bufA);
        radix_pass_fb<8 ><<<g, b, 0, stream>>>(wts, bufA, bufB);
        radix_pass_fb<16><<<g, b, 0, stream>>>(wts, bufB, bufA);
        radix_pass_fb<24><<<g, b, 0, stream>>>(wts, bufA, bufB);
        finalize_fb<<<g, b, 0, stream>>>(wts, bufB, out0, out1, out2);
    }
}

// Round 11
// 605.286 us; speedup vs baseline: 1.2258x; 1.0522x over previous
//
#include <hip/hip_runtime.h>
#include <stdint.h>

#define B    512
#define N    50257
#define BLK  512
#define NWAVE 8
#define TILE 8192
#define CHUNK 1024           // per-wave contiguous chunk = TILE/NWAVE
#define NGRP 16              // 64-elem groups per chunk
#define THRESH 0.4f

// Softmax weights are strictly positive floats: raw bit pattern is monotone
// in value. Complement -> ascending stable order == descending weight order,
// ties broken by ascending original index (stable LSD radix), matching
// jnp.argsort(-weights).
__device__ __forceinline__ uint32_t sort_key(float w) { return ~__float_as_uint(w); }

__device__ __forceinline__ void hist_elem(uint32_t* hw0, const float w) {
    const uint32_t key = sort_key(w);
    atomicAdd(hw0 + (key & 255u), 1u);
    atomicAdd(hw0 + 256 + ((key >> 8) & 255u), 1u);
    atomicAdd(hw0 + 512 + ((key >> 16) & 255u), 1u);
    atomicAdd(hw0 + 768 + ((key >> 24) & 255u), 1u);
}

// ---------------------------------------------------------------------------
// Histogram kernel (per-wave-private bins, plain LDS atomics, float4 sweep).
// ---------------------------------------------------------------------------
__global__ __launch_bounds__(BLK) void hist4_fast(const float* __restrict__ wts,
                                                  uint32_t* __restrict__ histWS) {
    __shared__ uint32_t hw[NWAVE][4][256];   // 32 KB
    __shared__ uint32_t wtot[4];
    const int row = blockIdx.x;
    const size_t base = (size_t)row * N;
    const int tid = threadIdx.x;
    const int lane = tid & 63;
    const int wv = tid >> 6;

    {   // zero own wave's slice (no cross-wave access -> no barrier needed)
        uint32_t* p = &hw[wv][0][0];
        for (int j = lane; j < 4 * 256; j += 64) p[j] = 0;
    }
    uint32_t* hw0 = &hw[wv][0][0];

    // vectorized sweep (order-independent): head to 16B alignment, f4 body, tail
    const int head = (int)((4 - (base & 3)) & 3);
    for (int i = tid; i < head; i += BLK) hist_elem(hw0, wts[base + i]);
    const int nvec = (N - head) >> 2;
    const float4* v4 = (const float4*)(wts + base + head);
    for (int iv = tid; iv < nvec; iv += BLK) {
        const float4 f = v4[iv];
        hist_elem(hw0, f.x); hist_elem(hw0, f.y);
        hist_elem(hw0, f.z); hist_elem(hw0, f.w);
    }
    for (int i = head + 4 * nvec + tid; i < N; i += BLK) hist_elem(hw0, wts[base + i]);
    __syncthreads();

    for (int p = 0; p < 4; ++p) {
        uint32_t cnt = 0;
        if (tid < 256) {
            #pragma unroll
            for (int w = 0; w < NWAVE; ++w) cnt += hw[w][p][tid];
        }
        // exclusive scan over 256 bins: intra-wave shfl + cross-wave via wtot
        uint32_t incl = cnt;
        #pragma unroll
        for (int o = 1; o < 64; o <<= 1) {
            const uint32_t u = __shfl_up(incl, o);
            if (lane >= o) incl += u;
        }
        if (tid < 256 && lane == 63) wtot[tid >> 6] = incl;
        __syncthreads();
        if (tid < 256) {
            uint32_t prefix = 0;
            const int w4 = tid >> 6;
            #pragma unroll
            for (int w2 = 0; w2 < 4; ++w2) if (w2 < w4) prefix += wtot[w2];
            histWS[((size_t)row * 4 + p) * 256 + tid] = prefix + incl - cnt;
        }
        __syncthreads();   // protect wtot reuse
    }
}

// ---------------------------------------------------------------------------
// TIER A: r5-proven pipelined wave-private scatter; global payload SPLIT into
// key (u32) + idx (u16) streams. LAST pass writes idx directly as FLOAT
// (v_cvt in-register) so finalize never touches the out0 region again.
// TILE=8192, grid=B (1 block/row, 2/CU) — r9 showed more blocks thrash L3
// reuse; prefetch issues AFTER the layout barrier (r6 showed earlier breaks
// producer->consumer reuse).
// ---------------------------------------------------------------------------
template <int SHIFT, bool FIRST, bool LAST>
__global__ __launch_bounds__(BLK, 4) void scatter_pl(const float* __restrict__ wts,
                                                     const uint32_t* __restrict__ keySrc,
                                                     const uint16_t* __restrict__ idxSrc,
                                                     uint32_t* __restrict__ keyDst,
                                                     uint16_t* __restrict__ idxDst,
                                                     float* __restrict__ outIdxF,
                                                     float* __restrict__ outW,
                                                     const uint32_t* __restrict__ histWS) {
    __shared__ __align__(16) unsigned long long stage[TILE];  // 64 KB
    __shared__ uint32_t waveCnt[NWAVE][256];                  //  8 KB
    __shared__ uint32_t delta[256];                           //  1 KB
    __shared__ uint32_t wtot[4];

    const int row = blockIdx.x;
    const size_t base = (size_t)row * N;
    const int tid  = threadIdx.x;
    const int lane = tid & 63;
    const int wv   = tid >> 6;
    constexpr int PASS = SHIFT / 8;
    constexpr int KS = SHIFT + 16;   // digit position within packed pair

    uint32_t curReg = 0;             // this thread's bucket cursor (tid<256)
    if (tid < 256) curReg = histWS[((size_t)row * 4 + PASS) * 256 + tid];

    const int numTiles = (N + TILE - 1) / TILE;   // 7

    unsigned long long pairN[NGRP];
    {   // prefetch tile 0 (always full: TILE < N)
        const int cb = wv * CHUNK;
        #pragma unroll
        for (int g = 0; g < NGRP; ++g) {
            const int i = cb + g * 64 + lane;
            pairN[g] = FIRST ? (((unsigned long long)sort_key(wts[base + i]) << 16) | (uint32_t)i)
                             : (((unsigned long long)keySrc[base + i] << 16) | (uint32_t)idxSrc[base + i]);
        }
    }

    for (int t = 0; t < numTiles; ++t) {
        const int tbase = t * TILE;
        const int tileLen = (N - tbase < TILE) ? (N - tbase) : TILE;
        const int cbase = tbase + wv * CHUNK;
        const bool full = (tbase + TILE <= N);

        // ---- Phase 1: rank own chunk from registers (NO barriers) ----
        // Safe to zero own waveCnt row here: phase 2 of tile t-1 finished
        // reading all rows before barrier (C,t-1) < (D,t-1).
        {
            uint4* z = (uint4*)&waveCnt[wv][0];
            z[lane] = make_uint4(0u, 0u, 0u, 0u);
        }
        unsigned long long pairR[NGRP];
        uint32_t posR[NGRP];
        #pragma unroll
        for (int g = 0; g < NGRP; ++g) pairR[g] = pairN[g];

        if (full) {
            #pragma unroll
            for (int g = 0; g < NGRP; ++g) {
                const uint32_t d = (uint32_t)(pairR[g] >> KS) & 255u;
                unsigned long long peers = ~0ull;
                #pragma unroll
                for (int bb = 0; bb < 8; ++bb) {
                    const unsigned long long bit = __ballot((d >> bb) & 1u);
                    peers &= ((d >> bb) & 1u) ? bit : ~bit;
                }
                const unsigned long long lower = peers & ((1ull << lane) - 1ull);
                const uint32_t cnt = waveCnt[wv][d];
                posR[g] = cnt + (uint32_t)__popcll(lower);
                if (lower == 0ull) waveCnt[wv][d] = cnt + (uint32_t)__popcll(peers);
            }
        } else {
            #pragma unroll
            for (int g = 0; g < NGRP; ++g) {
                const int i = cbase + g * 64 + lane;
                const bool valid = (i < N);
                const uint32_t d = (uint32_t)(pairR[g] >> KS) & 255u;
                unsigned long long peers = __ballot(valid);
                #pragma unroll
                for (int bb = 0; bb < 8; ++bb) {
                    const unsigned long long bit = __ballot((d >> bb) & 1u);
                    peers &= ((d >> bb) & 1u) ? bit : ~bit;
                }
                const unsigned long long lower = peers & ((1ull << lane) - 1ull);
                uint32_t cnt = 0;
                if (valid) cnt = waveCnt[wv][d];
                posR[g] = cnt + (uint32_t)__popcll(lower);
                if (valid && lower == 0ull) waveCnt[wv][d] = cnt + (uint32_t)__popcll(peers);
            }
        }
        __syncthreads();                               // (A) ranks done; stage(t-1) drained

        // ---- Phase 2: tile layout (shfl scan, 2 barriers) ----
        uint32_t run = 0;
        if (tid < 256) {
            #pragma unroll
            for (int w = 0; w < NWAVE; ++w) {
                const uint32_t c = waveCnt[w][tid];
                waveCnt[w][tid] = run;                 // excl offset across waves
                run += c;
            }
        }
        uint32_t incl = run;
        #pragma unroll
        for (int o = 1; o < 64; o <<= 1) {
            const uint32_t u = __shfl_up(incl, o);
            if (lane >= o) incl += u;
        }
        if (tid < 256 && lane == 63) wtot[tid >> 6] = incl;
        __syncthreads();                               // (B)
        if (tid < 256) {
            uint32_t prefix = 0;
            const int w4 = tid >> 6;
            #pragma unroll
            for (int w2 = 0; w2 < 4; ++w2) if (w2 < w4) prefix += wtot[w2];
            const uint32_t ts = prefix + incl - run;   // tileStart[tid]
            delta[tid] = curReg - ts;                  // global = delta[d] + p
            curReg += run;
            #pragma unroll
            for (int w = 0; w < NWAVE; ++w) waveCnt[w][tid] += ts;
        }
        __syncthreads();                               // (C) layout ready

        // ---- Prefetch next tile (latency hides under phases 3-4; r5 spot) ----
        if (t + 1 < numTiles) {
            const int ncb = (t + 1) * TILE + wv * CHUNK;
            if (ncb + CHUNK <= N) {                    // wave-uniform branch
                #pragma unroll
                for (int g = 0; g < NGRP; ++g) {
                    const int i = ncb + g * 64 + lane;
                    pairN[g] = FIRST ? (((unsigned long long)sort_key(wts[base + i]) << 16) | (uint32_t)i)
                                     : (((unsigned long long)keySrc[base + i] << 16) | (uint32_t)idxSrc[base + i]);
                }
            } else {
                #pragma unroll
                for (int g = 0; g < NGRP; ++g) {
                    const int i = ncb + g * 64 + lane;
                    unsigned long long pair = 0;
                    if (i < N)
                        pair = FIRST ? (((unsigned long long)sort_key(wts[base + i]) << 16) | (uint32_t)i)
                                     : (((unsigned long long)keySrc[base + i] << 16) | (uint32_t)idxSrc[base + i]);
                    pairN[g] = pair;
                }
            }
        }

        // ---- Phase 3: stage bucket-contiguous in LDS ----
        if (full) {
            #pragma unroll
            for (int g = 0; g < NGRP; ++g) {
                const uint32_t d = (uint32_t)(pairR[g] >> KS) & 255u;
                stage[waveCnt[wv][d] + posR[g]] = pairR[g];
            }
        } else {
            #pragma unroll
            for (int g = 0; g < NGRP; ++g) {
                const int i = cbase + g * 64 + lane;
                if (i < N) {
                    const uint32_t d = (uint32_t)(pairR[g] >> KS) & 255u;
                    stage[waveCnt[wv][d] + posR[g]] = pairR[g];
                }
            }
        }
        __syncthreads();                               // (D) stage complete

        // ---- Phase 4: 2-wide flush to SPLIT key/idx streams ----
        const int tileLenEven = tileLen & ~1;
        for (int p0 = 2 * tid; p0 < tileLenEven; p0 += 2 * BLK) {
            const ulonglong2 two = *(const ulonglong2*)&stage[p0];   // 16B aligned
            const uint32_t d0 = (uint32_t)(two.x >> KS) & 255u;
            const uint32_t d1 = (uint32_t)(two.y >> KS) & 255u;
            const uint32_t g0 = delta[d0] + (uint32_t)p0;
            const uint32_t g1 = delta[d1] + (uint32_t)p0 + 1u;
            if (LAST) {
                outIdxF[base + g0] = (float)(uint32_t)(two.x & 0xFFFFull);
                outW[base + g0]    = __uint_as_float(~(uint32_t)(two.x >> 16));
                outIdxF[base + g1] = (float)(uint32_t)(two.y & 0xFFFFull);
                outW[base + g1]    = __uint_as_float(~(uint32_t)(two.y >> 16));
            } else {
                keyDst[base + g0] = (uint32_t)(two.x >> 16);
                idxDst[base + g0] = (uint16_t)(two.x & 0xFFFFull);
                keyDst[base + g1] = (uint32_t)(two.y >> 16);
                idxDst[base + g1] = (uint16_t)(two.y & 0xFFFFull);
            }
        }
        for (int p = tileLenEven + tid; p < tileLen; p += BLK) {     // odd tail
            const unsigned long long pair = stage[p];
            const uint32_t d = (uint32_t)(pair >> KS) & 255u;
            const uint32_t g = delta[d] + (uint32_t)p;
            if (LAST) {
                outIdxF[base + g] = (float)(uint32_t)(pair & 0xFFFFull);
                outW[base + g]    = __uint_as_float(~(uint32_t)(pair >> 16));
            } else {
                keyDst[base + g] = (uint32_t)(pair >> 16);
                idxDst[base + g] = (uint16_t)(pair & 0xFFFFull);
            }
        }
        // no trailing barrier: (A) of the next tile separates flush(t) reads
        // from stage(t+1) writes and delta(t+1) updates.
    }
}

// ---------------------------------------------------------------------------
// Finalize: scan sorted w (early exit), then normalize out1 IN PLACE.
// out0 already holds float idx (written by pass 4) — never touched here.
// ---------------------------------------------------------------------------
__global__ __launch_bounds__(BLK) void finalize_row(float* __restrict__ out1,
                                                    float* __restrict__ out2) {
    __shared__ float waveSum[NWAVE];
    __shared__ int   waveFirst[NWAVE];
    __shared__ float waveCum[NWAVE];
    __shared__ int   s_k;
    __shared__ float s_total;

    const int row = blockIdx.x;
    const size_t base = (size_t)row * N;
    const int tid  = threadIdx.x;
    const int lane = tid & 63;
    const int wv   = tid >> 6;

    if (tid == 0) { s_k = -1; s_total = 0.f; }
    __syncthreads();

    // Phase A: block-wide running cumsum with early exit
    float carry = 0.f;
    const int numTiles = (N + BLK - 1) / BLK;
    for (int t = 0; t < numTiles; ++t) {
        const int i = t * BLK + tid;
        const bool valid = (i < N);
        float w = valid ? out1[base + i] : 0.f;

        float s = w;
        #pragma unroll
        for (int o = 1; o < 64; o <<= 1) {
            float u = __shfl_up(s, o);
            if (lane >= o) s += u;
        }
        if (lane == 63) waveSum[wv] = s;
        __syncthreads();

        float prefix = 0.f, blockTot = 0.f;
        #pragma unroll
        for (int w2 = 0; w2 < NWAVE; ++w2) {
            float t2 = waveSum[w2];
            if (w2 < wv) prefix += t2;
            blockTot += t2;
        }
        const float cum = carry + prefix + s;

        const bool exceed = valid && (cum > THRESH);
        const unsigned long long bal = __ballot(exceed);
        const int fl = (bal == 0ull) ? 64 : (__ffsll(bal) - 1);
        if (lane == 0) waveFirst[wv] = fl;
        if (fl < 64 && lane == fl) waveCum[wv] = cum;
        __syncthreads();
        if (tid == 0) {
            for (int w2 = 0; w2 < NWAVE; ++w2) {
                if (waveFirst[w2] < 64) {
                    s_k = t * BLK + w2 * 64 + waveFirst[w2] + 1;
                    s_total = waveCum[w2];
                    break;
                }
            }
        }
        __syncthreads();
        if (s_k >= 0) break;
        carry += blockTot;
        __syncthreads();
    }

    int k = s_k;
    float total = s_total;
    if (k < 0) { k = N; total = carry; }
    const float inv = 1.0f / total;

    // Phase B: in-place normalize out1 only (per-thread read-before-write).
    const int head = (int)((4 - (base & 3)) & 3);     // to 16B alignment
    const int nvec = (N - head) >> 2;
    const int vend = head + 4 * nvec;

    for (int i = tid; i < head; i += BLK) {
        const float w = out1[base + i];
        out1[base + i] = (i < k) ? (w * inv) : 0.f;
    }
    float4* o1v = (float4*)(out1 + base + head);
    for (int v = tid; v < nvec; v += BLK) {
        const float4 wv4 = o1v[v];
        const int i = head + 4 * v;
        float4 o1;
        o1.x = (i + 0 < k) ? wv4.x * inv : 0.f;
        o1.y = (i + 1 < k) ? wv4.y * inv : 0.f;
        o1.z = (i + 2 < k) ? wv4.z * inv : 0.f;
        o1.w = (i + 3 < k) ? wv4.w * inv : 0.f;
        o1v[v] = o1;
    }
    for (int i = vend + tid; i < N; i += BLK) {
        const float w = out1[base + i];
        out1[base + i] = (i < k) ? (w * inv) : 0.f;
    }
    if (tid == 0) out2[row] = (float)k;
}

// ---------------------------------------------------------------------------
// FALLBACK (round-1 proven): gather-based, no workspace.
// ---------------------------------------------------------------------------
template <int SHIFT>
__global__ __launch_bounds__(BLK) void radix_pass_fb(const float* __restrict__ wts,
                                                     const uint32_t* __restrict__ src,
                                                     uint32_t* __restrict__ dst) {
    __shared__ uint32_t hist[256];
    __shared__ uint32_t scanb[256];
    __shared__ uint32_t running[256];
    __shared__ uint32_t waveCnt32[NWAVE][256];

    const int row = blockIdx.x;
    const size_t base = (size_t)row * N;
    const int tid  = threadIdx.x;
    const int lane = tid & 63;
    const int wv   = tid >> 6;

    if (tid < 256) hist[tid] = 0;
    __syncthreads();
    for (int i = tid; i < N; i += BLK) {
        uint32_t idx = (SHIFT == 0) ? (uint32_t)i : src[base + i];
        uint32_t d = (sort_key(wts[base + idx]) >> SHIFT) & 255u;
        atomicAdd(&hist[d], 1u);
    }
    __syncthreads();

    if (tid < 256) scanb[tid] = hist[tid];
    __syncthreads();
    for (int off = 1; off < 256; off <<= 1) {
        uint32_t add = 0;
        if (tid < 256 && tid >= off) add = scanb[tid - off];
        __syncthreads();
        if (tid < 256) scanb[tid] += add;
        __syncthreads();
    }
    if (tid < 256) running[tid] = (tid == 0) ? 0u : scanb[tid - 1];
    __syncthreads();

    const int numTiles = (N + BLK - 1) / BLK;
    for (int t = 0; t < numTiles; ++t) {
        for (int j = tid; j < NWAVE * 256; j += BLK) ((uint32_t*)waveCnt32)[j] = 0;
        __syncthreads();

        const int i = t * BLK + tid;
        const bool valid = (i < N);
        uint32_t idx = 0, d = 0;
        if (valid) {
            idx = (SHIFT == 0) ? (uint32_t)i : src[base + i];
            d = (sort_key(wts[base + idx]) >> SHIFT) & 255u;
        }
        unsigned long long peers = __ballot(valid);
        #pragma unroll
        for (int b = 0; b < 8; ++b) {
            unsigned long long bit = __ballot(valid && ((d >> b) & 1u));
            peers &= ((d >> b) & 1u) ? bit : ~bit;
        }
        const unsigned long long lower = peers & ((1ull << lane) - 1ull);
        const uint32_t rank = (uint32_t)__popcll(lower);
        if (valid && lower == 0ull) waveCnt32[wv][d] = (uint32_t)__popcll(peers);
        __syncthreads();

        if (tid < 256) {
            uint32_t s = running[tid];
            #pragma unroll
            for (int w = 0; w < NWAVE; ++w) {
                uint32_t c = waveCnt32[w][tid];
                waveCnt32[w][tid] = s;
                s += c;
            }
            running[tid] = s;
        }
        __syncthreads();

        if (valid) {
            uint32_t pos = waveCnt32[wv][d] + rank;
            dst[base + pos] = idx;
        }
        __syncthreads();
    }
}

__global__ __launch_bounds__(BLK) void finalize_fb(const float* __restrict__ wts,
                                                   const uint32_t* __restrict__ sidx,
                                                   float* __restrict__ out0,
                                                   float* __restrict__ out1,
                                                   float* __restrict__ out2) {
    __shared__ float waveSum[NWAVE];
    __shared__ int   waveFirst[NWAVE];
    __shared__ float waveCum[NWAVE];
    __shared__ int   s_k;
    __shared__ float s_total;

    const int row = blockIdx.x;
    const size_t base = (size_t)row * N;
    const int tid  = threadIdx.x;
    const int lane = tid & 63;
    const int wv   = tid >> 6;

    if (tid == 0) { s_k = -1; s_total = 0.f; }
    __syncthreads();

    float carry = 0.f;
    const int numTiles = (N + BLK - 1) / BLK;
    for (int t = 0; t < numTiles; ++t) {
        const int i = t * BLK + tid;
        const bool valid = (i < N);
        float w = valid ? wts[base + sidx[base + i]] : 0.f;

        float s = w;
        #pragma unroll
        for (int o = 1; o < 64; o <<= 1) {
            float u = __shfl_up(s, o);
            if (lane >= o) s += u;
        }
        if (lane == 63) waveSum[wv] = s;
        __syncthreads();

        float prefix = 0.f, blockTot = 0.f;
        #pragma unroll
        for (int w2 = 0; w2 < NWAVE; ++w2) {
            float t2 = waveSum[w2];
            if (w2 < wv) prefix += t2;
            blockTot += t2;
        }
        const float cum = carry + prefix + s;

        const bool exceed = valid && (cum > THRESH);
        const unsigned long long bal = __ballot(exceed);
        const int fl = (bal == 0ull) ? 64 : (__ffsll(bal) - 1);
        if (lane == 0) waveFirst[wv] = fl;
        if (fl < 64 && lane == fl) waveCum[wv] = cum;
        __syncthreads();
        if (tid == 0) {
            for (int w2 = 0; w2 < NWAVE; ++w2) {
                if (waveFirst[w2] < 64) {
                    s_k = t * BLK + w2 * 64 + waveFirst[w2] + 1;
                    s_total = waveCum[w2];
                    break;
                }
            }
        }
        __syncthreads();
        if (s_k >= 0) break;
        carry += blockTot;
        __syncthreads();
    }

    int k = s_k;
    float total = s_total;
    if (k < 0) { k = N; total = carry; }

    for (int i = tid; i < N; i += BLK) {
        const uint32_t idx = sidx[base + i];
        const float w = wts[base + idx];
        out0[base + i] = (float)idx;
        out1[base + i] = (i < k) ? (w / total) : 0.f;
    }
    if (tid == 0) out2[row] = (float)k;
}

// ---------------------------------------------------------------------------

extern "C" void kernel_launch(void* const* d_in, const int* in_sizes, int n_in,
                              void* d_out, int out_size, void* d_ws, size_t ws_size,
                              hipStream_t stream) {
    const float* wts = (const float*)d_in[0];
    float* out0 = (float*)d_out;                       // sorted_idx (as f32)
    float* out1 = out0 + (size_t)B * N;                // norm_w
    float* out2 = out0 + 2 * (size_t)B * N;            // k (as f32)

    const size_t KEY_BYTES  = (size_t)B * N * 4;       // 102,926,336
    const size_t IDX_BYTES  = (size_t)B * N * 2;       //  51,463,168
    const size_t HIST_BYTES = (size_t)B * 4 * 256 * 4; //   2,097,152
    const size_t WS_NEED = KEY_BYTES + IDX_BYTES + HIST_BYTES;

    dim3 g(B), b(BLK);
    if (ws_size >= WS_NEED) {
        // Tier A: pipelined wave-private path, 6-byte split payload; pass 4
        // writes float idx directly. Ping-pong: buffer A = {keyWS, idxWS} in
        // d_ws; buffer B = {key in out0 region, idx in out1 region} of d_out.
        uint8_t* ws = (uint8_t*)d_ws;
        uint32_t* keyWS  = (uint32_t*)ws;
        uint16_t* idxWS  = (uint16_t*)(ws + KEY_BYTES);
        uint32_t* histWS = (uint32_t*)(ws + KEY_BYTES + IDX_BYTES);
        uint32_t* keyOUT = (uint32_t*)out0;
        uint16_t* idxOUT = (uint16_t*)out1;

        hist4_fast<<<g, b, 0, stream>>>(wts, histWS);
        scatter_pl<0,  true,  false><<<g, b, 0, stream>>>(wts, nullptr, nullptr, keyWS, idxWS, nullptr, nullptr, histWS);
        scatter_pl<8,  false, false><<<g, b, 0, stream>>>(nullptr, keyWS, idxWS, keyOUT, idxOUT, nullptr, nullptr, histWS);
        scatter_pl<16, false, false><<<g, b, 0, stream>>>(nullptr, keyOUT, idxOUT, keyWS, idxWS, nullptr, nullptr, histWS);
        scatter_pl<24, false, true ><<<g, b, 0, stream>>>(nullptr, keyWS, idxWS, nullptr, nullptr, out0, out1, histWS);
        finalize_row<<<g, b, 0, stream>>>(out1, out2);
    } else {
        // Fallback: no-workspace gather path (round-1 proven).
        uint32_t* bufA = (uint32_t*)out0;
        uint32_t* bufB = (uint32_t*)out1;
        radix_pass_fb<0 ><<<g, b, 0, stream>>>(wts, nullptr, bufA);
        radix_pass_fb<8 ><<<g, b, 0, stream>>>(wts, bufA, bufB);
        radix_pass_fb<16><<<g, b, 0, stream>>>(wts, bufB, bufA);
        radix_pass_fb<24><<<g, b, 0, stream>>>(wts, bufA, bufB);
        finalize_fb<<<g, b, 0, stream>>>(wts, bufB, out0, out1, out2);
    }
}